// Round 6
// baseline (952.989 us; speedup 1.0000x reference)
//
#include <hip/hip_runtime.h>
#include <math.h>

#define B_  64
#define D_  256
#define H_  512
#define N_  16384
#define M_  64
#define S_  3
#define EPS_ 1e-4f

__device__ __forceinline__ float sigmoidf_(float x) { return 1.0f / (1.0f + expf(-x)); }

// ---------------------------------------------------------------------------
// K1/K7: head params.  One block per batch, 8 waves (512 thr). Wave-per-row
// GEMV: lane l holds h[l+64j]; each wave reduces rows r = wid, wid+8, ...
// ---------------------------------------------------------------------------
template <bool WITH_W>
__global__ __launch_bounds__(512) void head_params_kernel(
    const float* __restrict__ h,
    const float* __restrict__ Wk, const float* __restrict__ bk,
    const float* __restrict__ Wc, const float* __restrict__ bc,
    const float* __restrict__ Ws, const float* __restrict__ bs,
    const float* __restrict__ Ww, const float* __restrict__ bw,
    float* __restrict__ k_out, float* __restrict__ nk_out,
    float* __restrict__ s_out,
    float* __restrict__ beta_out, float* __restrict__ g_out, float* __restrict__ gamma_out,
    float* __restrict__ e_out, float* __restrict__ a_out)
{
    const int b = blockIdx.x;
    const int tid = threadIdx.x;
    const int lane = tid & 63;
    const int wid = tid >> 6;
    __shared__ float raw[198];

    float h8[8];
    #pragma unroll
    for (int j = 0; j < 8; ++j) h8[j] = h[b * H_ + lane + 64 * j];

    const int count = WITH_W ? 198 : 70;
    for (int r = wid; r < count; r += 8) {
        const float* wrow;
        float bias;
        if (r < 64)       { wrow = Wk + r * H_;        bias = bk[r]; }
        else if (r < 67)  { wrow = Wc + (r - 64) * H_; bias = bc[r - 64]; }
        else if (r < 70)  { wrow = Ws + (r - 67) * H_; bias = bs[r - 67]; }
        else              { wrow = Ww + (r - 70) * H_; bias = bw[r - 70]; }
        float acc = 0.f;
        #pragma unroll
        for (int j = 0; j < 8; ++j) acc += wrow[lane + 64 * j] * h8[j];
        for (int off = 32; off >= 1; off >>= 1) acc += __shfl_xor(acc, off);
        if (lane == 0) raw[r] = acc + bias;
    }
    __syncthreads();

    if (tid < 64) {
        float kv = tanhf(raw[tid]);
        k_out[b * 64 + tid] = kv;
        float sq = kv * kv;
        for (int off = 32; off >= 1; off >>= 1) sq += __shfl_xor(sq, off);
        if (tid == 0) nk_out[b] = sqrtf(sq) + EPS_;
    } else if (tid == 64) {
        float c0 = raw[64], c1 = raw[65], c2 = raw[66];
        beta_out[b]  = fmaxf(c0, 0.f) + EPS_;
        g_out[b]     = sigmoidf_(c1);
        gamma_out[b] = fmaxf(c2, 0.f) + 1.f + EPS_;
    } else if (tid == 65) {
        float s0 = raw[67], s1 = raw[68], s2 = raw[69];
        float mx = fmaxf(s0, fmaxf(s1, s2));
        float e0 = expf(s0 - mx), e1 = expf(s1 - mx), e2 = expf(s2 - mx);
        float inv = 1.f / (e0 + e1 + e2);
        s_out[b * 3 + 0] = e0 * inv;
        s_out[b * 3 + 1] = e1 * inv;
        s_out[b * 3 + 2] = e2 * inv;
    }
    if (WITH_W && tid >= 128 && tid < 192) {
        int m = tid - 128;
        e_out[b * 64 + m] = sigmoidf_(raw[70 + m]);
        a_out[b * 64 + m] = raw[134 + m];
    }
}

// ---------------------------------------------------------------------------
// K2/K8: score pass.  E[b,n] = exp(beta * (k.mem_row)/(nM*nk)) -- NO max
// subtraction needed: |beta*dot/(nM*nk)| <= beta (Cauchy-Schwarz), beta is
// O(1) for this distribution, exp can't overflow fp32 below x=88.
// Per-block partial of sum(E) atomicAdd'ed into sumE[b].
// MODE 0: compute+store nM.  MODE 1: load nM; also finalize previous head:
// head_prev[n] = sharp_prev[n]/ssum_prev[b].
// ---------------------------------------------------------------------------
template <int MODE>
__global__ __launch_bounds__(256) void scoreE_kernel(
    const float* __restrict__ memory,
    const float* __restrict__ k,
    const float* __restrict__ beta_a,
    const float* __restrict__ nk_a,
    float* __restrict__ Eout,
    float* __restrict__ nMbuf,
    float* __restrict__ sumE,
    const float* __restrict__ sharp_prev,
    const float* __restrict__ ssum_prev,
    float* __restrict__ head_prev)
{
    __shared__ float red[4];
    const int tid = threadIdx.x;
    const int lane = tid & 63;
    const int wid = tid >> 6;
    const int grp = lane >> 4;
    const int m16 = lane & 15;
    const int b = blockIdx.x >> 8;
    const int nbase = (blockIdx.x & 255) * 64;
    const float4 k4 = ((const float4*)(k + b * 64))[m16];
    const float beta = beta_a[b], nk = nk_a[b];
    const int slot = wid * 4 + grp;
    const size_t bbase = (size_t)b * N_;

    if (MODE == 1) {
        if (tid < 64) {
            const float rinv = 1.f / ssum_prev[b];
            head_prev[bbase + nbase + tid] = sharp_prev[bbase + nbase + tid] * rinv;
        }
    }

    float lsum = 0.f;
    #pragma unroll
    for (int it = 0; it < 4; ++it) {
        const int n = nbase + it * 16 + slot;
        const float4 m4 = ((const float4*)(memory + (bbase + n) * 64))[m16];
        float d  = m4.x * k4.x + m4.y * k4.y + m4.z * k4.z + m4.w * k4.w;
        float sq = 0.f;
        if (MODE == 0) sq = m4.x * m4.x + m4.y * m4.y + m4.z * m4.z + m4.w * m4.w;
        for (int off = 8; off >= 1; off >>= 1) {
            d += __shfl_xor(d, off);
            if (MODE == 0) sq += __shfl_xor(sq, off);
        }
        if (m16 == 0) {
            float nMv;
            if (MODE == 0) {
                nMv = sqrtf(sq) + EPS_;
                nMbuf[bbase + n] = nMv;
            } else {
                nMv = nMbuf[bbase + n];
            }
            const float E = expf(beta * d / (nMv * nk));
            Eout[bbase + n] = E;
            lsum += E;
        }
    }
    for (int off = 32; off >= 1; off >>= 1) lsum += __shfl_xor(lsum, off);
    if (lane == 0) red[wid] = lsum;
    __syncthreads();
    if (tid == 0) atomicAdd(&sumE[b], red[0] + red[1] + red[2] + red[3]);
}

// ---------------------------------------------------------------------------
// K3/K9: conv+sharpen (and, if WITH_MREAD, fused unnormalized M_read memory
// pass).  Block = 256 consecutive n of one batch; grid = B*64.
// content p[n] = E[n]/sumE; inter = g*p + (1-g)*w_tm1; 3-tap circular conv;
// sharp = max(conv,1e-8)^gamma -> global + LDS; partial sum(sharp) -> ssum[b].
// Phase B (WITH_MREAD): M_read_un[b,:] += sum_n sharp[n]*mem[n,:] (atomics);
// normalization by 1/ssum happens in the gates GEMM.
// ---------------------------------------------------------------------------
template <bool WITH_MREAD>
__global__ __launch_bounds__(256) void conv_kernel(
    const float* __restrict__ memory,
    const float* __restrict__ E,
    const float* __restrict__ w_tm1,
    const float* __restrict__ sumE,
    const float* __restrict__ g_a, const float* __restrict__ gamma_a,
    const float* __restrict__ s_a,
    float* __restrict__ sharp,
    float* __restrict__ ssum,
    float* __restrict__ M_read_un)
{
    __shared__ float inter_sm[258];
    __shared__ float sharp_sm[256];
    __shared__ float red[4];
    __shared__ float4 part[64];
    const int tid = threadIdx.x;
    const int b = blockIdx.x >> 6;
    const int nbase = (blockIdx.x & 63) * 256;
    const size_t base = (size_t)b * N_;
    const float ginv = 1.f / sumE[b];
    const float g = g_a[b], gamma = gamma_a[b];
    const float s0 = s_a[b * 3 + 0], s1 = s_a[b * 3 + 1], s2 = s_a[b * 3 + 2];

    {
        const int n = nbase + tid;
        inter_sm[tid + 2] = g * E[base + n] * ginv + (1.f - g) * w_tm1[base + n];
        if (tid < 2) {
            const int nh = (nbase + N_ - 2 + tid) & (N_ - 1);
            inter_sm[tid] = g * E[base + nh] * ginv + (1.f - g) * w_tm1[base + nh];
        }
    }
    __syncthreads();
    {
        const float conv = s2 * inter_sm[tid + 2] + s1 * inter_sm[tid + 1]
                         + s0 * inter_sm[tid];
        const float v = powf(fmaxf(conv, 1e-8f), gamma);
        sharp_sm[tid] = v;
        sharp[base + nbase + tid] = v;
        float ls = v;
        for (int off = 32; off >= 1; off >>= 1) ls += __shfl_xor(ls, off);
        if ((tid & 63) == 0) red[tid >> 6] = ls;
    }
    __syncthreads();
    if (tid == 0) atomicAdd(&ssum[b], red[0] + red[1] + red[2] + red[3]);

    if (WITH_MREAD) {
        const int lane = tid & 63;
        const int wid = tid >> 6;
        const int grp = lane >> 4;
        const int m16 = lane & 15;
        const int slot = wid * 4 + grp;      // 0..15
        float4 acc = make_float4(0.f, 0.f, 0.f, 0.f);
        #pragma unroll 4
        for (int it = 0; it < 16; ++it) {
            const int nl = it * 16 + slot;   // local row 0..255
            const float w = sharp_sm[nl];
            const float4 m4 = ((const float4*)(memory + (base + nbase + nl) * 64))[m16];
            acc.x += w * m4.x; acc.y += w * m4.y; acc.z += w * m4.z; acc.w += w * m4.w;
        }
        for (int off = 32; off >= 16; off >>= 1) {
            acc.x += __shfl_xor(acc.x, off);
            acc.y += __shfl_xor(acc.y, off);
            acc.z += __shfl_xor(acc.z, off);
            acc.w += __shfl_xor(acc.w, off);
        }
        if (lane < 16) part[wid * 16 + lane] = acc;
        __syncthreads();
        if (tid < 16) {
            float4 t = part[tid];
            for (int w2 = 1; w2 < 4; ++w2) {
                const float4 q = part[w2 * 16 + tid];
                t.x += q.x; t.y += q.y; t.z += q.z; t.w += q.w;
            }
            atomicAdd(&M_read_un[b * 64 + tid * 4 + 0], t.x);
            atomicAdd(&M_read_un[b * 64 + tid * 4 + 1], t.y);
            atomicAdd(&M_read_un[b * 64 + tid * 4 + 2], t.z);
            atomicAdd(&M_read_un[b * 64 + tid * 4 + 3], t.w);
        }
    }
}

// ---------------------------------------------------------------------------
// K4: gates split-K GEMM.  M_read chunk (c==4) is UNNORMALIZED; scaled here
// by 1/ssum_r[row].  Grid = 13*32 blocks.
// ---------------------------------------------------------------------------
__global__ __launch_bounds__(256) void gates_splitk_kernel(
    const float* __restrict__ inp,
    const float* __restrict__ M_read_un,
    const float* __restrict__ h_tm1,
    const float* __restrict__ W_ih,
    const float* __restrict__ W_hh,
    const float* __restrict__ ssum_r,
    float* __restrict__ gates)
{
    __shared__ __align__(16) float Xsm[64][68];
    __shared__ __align__(16) float Wsm[64][68];
    const int tid = threadIdx.x;
    const int jb = blockIdx.x & 31;
    const int c  = blockIdx.x >> 5;      // K-chunk 0..12
    const int j0 = jb * 64;

    #pragma unroll
    for (int i = 0; i < 4; ++i) {
        const int e = i * 256 + tid;
        const int row = e >> 4;
        const int c4 = e & 15;
        const float* xrow;
        if (c < 4)       xrow = inp       + row * 256 + c * 64;
        else if (c == 4) xrow = M_read_un + row * 64;
        else             xrow = h_tm1     + row * 512 + (c - 5) * 64;
        float4 v = ((const float4*)xrow)[c4];
        if (c == 4) {
            const float sc = 1.f / ssum_r[row];
            v.x *= sc; v.y *= sc; v.z *= sc; v.w *= sc;
        }
        const int kl = c4 * 4;
        Xsm[kl + 0][row] = v.x; Xsm[kl + 1][row] = v.y;
        Xsm[kl + 2][row] = v.z; Xsm[kl + 3][row] = v.w;
    }
    #pragma unroll
    for (int i = 0; i < 4; ++i) {
        const int e = i * 256 + tid;
        const int row = e >> 4;
        const int c4 = e & 15;
        const float* wrow;
        if (c < 5) wrow = W_ih + (j0 + row) * 320 + c * 64;
        else       wrow = W_hh + (j0 + row) * 512 + (c - 5) * 64;
        const float4 v = ((const float4*)wrow)[c4];
        const int kl = c4 * 4;
        Wsm[kl + 0][row] = v.x; Wsm[kl + 1][row] = v.y;
        Wsm[kl + 2][row] = v.z; Wsm[kl + 3][row] = v.w;
    }
    __syncthreads();

    const int tx = tid & 15, ty = tid >> 4;
    float acc[4][4] = {};
    #pragma unroll
    for (int k = 0; k < 64; ++k) {
        const float4 av = *((const float4*)&Xsm[k][ty * 4]);
        const float4 wv = *((const float4*)&Wsm[k][tx * 4]);
        acc[0][0] += av.x * wv.x; acc[0][1] += av.x * wv.y; acc[0][2] += av.x * wv.z; acc[0][3] += av.x * wv.w;
        acc[1][0] += av.y * wv.x; acc[1][1] += av.y * wv.y; acc[1][2] += av.y * wv.z; acc[1][3] += av.y * wv.w;
        acc[2][0] += av.z * wv.x; acc[2][1] += av.z * wv.y; acc[2][2] += av.z * wv.z; acc[2][3] += av.z * wv.w;
        acc[3][0] += av.w * wv.x; acc[3][1] += av.w * wv.y; acc[3][2] += av.w * wv.z; acc[3][3] += av.w * wv.w;
    }
    #pragma unroll
    for (int bi = 0; bi < 4; ++bi) {
        const int b = ty * 4 + bi;
        #pragma unroll
        for (int ji = 0; ji < 4; ++ji) {
            atomicAdd(&gates[b * 2048 + j0 + tx * 4 + ji], acc[bi][ji]);
        }
    }
}

// ---------------------------------------------------------------------------
// K5: LSTM elementwise (biases folded in here).
// ---------------------------------------------------------------------------
__global__ __launch_bounds__(256) void lstm_kernel(
    const float* __restrict__ gates,
    const float* __restrict__ b_ih, const float* __restrict__ b_hh,
    const float* __restrict__ c_tm1,
    float* __restrict__ h_out, float* __restrict__ c_out)
{
    const int idx = blockIdx.x * 256 + threadIdx.x;  // B*H
    const int b = idx >> 9, j = idx & 511;
    const float* gr = gates + b * 2048;
    const float i_ = sigmoidf_(gr[j]        + b_ih[j]        + b_hh[j]);
    const float f_ = sigmoidf_(gr[512 + j]  + b_ih[512 + j]  + b_hh[512 + j]);
    const float g_ = tanhf(   gr[1024 + j] + b_ih[1024 + j] + b_hh[1024 + j]);
    const float o_ = sigmoidf_(gr[1536 + j] + b_ih[1536 + j] + b_hh[1536 + j]);
    const float c = f_ * c_tm1[idx] + i_ * g_;
    c_out[idx] = c;
    h_out[idx] = o_ * tanhf(c);
}

// ---------------------------------------------------------------------------
// K10: M_out = memory*(1 - w*e) + w*a, w = sharpw[n]/ssum_w; whead finalized.
// ---------------------------------------------------------------------------
__global__ __launch_bounds__(256) void mout_norm_kernel(
    const float* __restrict__ memory,
    const float* __restrict__ sharpw,
    const float* __restrict__ ssum_w,
    const float* __restrict__ e,
    const float* __restrict__ a,
    float* __restrict__ whead,
    float* __restrict__ M_out)
{
    const size_t total = (size_t)B_ * N_ * 16;  // float4 count
    const size_t stride = (size_t)gridDim.x * 256;
    for (size_t idx = (size_t)blockIdx.x * 256 + threadIdx.x; idx < total; idx += stride) {
        const size_t nlin = idx >> 4;
        const int m4 = (int)(idx & 15);
        const int b = (int)(nlin >> 14);
        const float w = sharpw[nlin] * (1.f / ssum_w[b]);
        const float4 ev = ((const float4*)(e + b * 64))[m4];
        const float4 av = ((const float4*)(a + b * 64))[m4];
        const float4 mv = ((const float4*)memory)[idx];
        if (m4 == 0) whead[nlin] = w;   // same-thread: loads above precede store
        float4 o;
        o.x = mv.x * (1.f - w * ev.x) + w * av.x;
        o.y = mv.y * (1.f - w * ev.y) + w * av.y;
        o.z = mv.z * (1.f - w * ev.z) + w * av.z;
        o.w = mv.w * (1.f - w * ev.w) + w * av.w;
        ((float4*)M_out)[idx] = o;
    }
}

// ---------------------------------------------------------------------------
extern "C" void kernel_launch(void* const* d_in, const int* in_sizes, int n_in,
                              void* d_out, int out_size, void* d_ws, size_t ws_size,
                              hipStream_t stream)
{
    const float* inp       = (const float*)d_in[0];
    const float* h_tm1     = (const float*)d_in[1];
    const float* c_tm1     = (const float*)d_in[2];
    const float* read_tm1  = (const float*)d_in[3];
    const float* write_tm1 = (const float*)d_in[4];
    const float* memory    = (const float*)d_in[5];
    const float* W_ih = (const float*)d_in[6];  const float* b_ih = (const float*)d_in[7];
    const float* W_hh = (const float*)d_in[8];  const float* b_hh = (const float*)d_in[9];
    const float* W_rk = (const float*)d_in[10]; const float* b_rk = (const float*)d_in[11];
    const float* W_wk = (const float*)d_in[12]; const float* b_wk = (const float*)d_in[13];
    const float* W_rc = (const float*)d_in[14]; const float* b_rc = (const float*)d_in[15];
    const float* W_wc = (const float*)d_in[16]; const float* b_wc = (const float*)d_in[17];
    const float* W_rs = (const float*)d_in[18]; const float* b_rs = (const float*)d_in[19];
    const float* W_ws = (const float*)d_in[20]; const float* b_ws = (const float*)d_in[21];
    const float* W_w  = (const float*)d_in[22]; const float* b_w  = (const float*)d_in[23];

    float* out = (float*)d_out;
    float* h_out = out;                       // B*H
    float* c_out = out + 32768;               // B*H
    float* rhead = out + 65536;               // B*N (final written by scoreE<1>)
    float* whead = out + 65536 + 1048576;     // B*N (final written by mout)
    float* Mout  = out + 65536 + 2 * 1048576; // B*N*M (final written by mout)

    // Scratch aliased into output regions (each dead before final writer):
    float* E_r     = rhead;                   // scoreE0 writes; conv_r reads; scoreE1 overwrites w/ rhead
    float* sharp_r = whead;                   // conv_r writes; scoreE1 reads; conv_w overwrites
    float* E_w     = Mout;                    // scoreE1 writes; conv_w reads; mout overwrites
    float* nMbuf   = Mout + (size_t)B_ * N_;  // scoreE0 writes; scoreE1 reads; mout overwrites
    float* sharp_w = whead;                   // conv_w writes; mout reads then finalizes whead

    // Workspace layout (floats); first 135424 floats zeroed in one memset:
    // gates 131072, M_read_un 4096, sum_r 64, sum_w 64, ssum_r 64, ssum_w 64.
    float* ws = (float*)d_ws;
    float* gates     = ws;
    float* M_read_un = ws + 131072;
    float* sum_r     = ws + 135168;
    float* sum_w     = ws + 135232;
    float* ssum_r    = ws + 135296;
    float* ssum_w    = ws + 135360;
    float* rk        = ws + 135424;
    float* wk        = ws + 139520;
    float* e_buf     = ws + 143616;
    float* a_buf     = ws + 147712;
    float* rs        = ws + 151808;
    float* wss       = ws + 152000;
    float* rbeta     = ws + 152192;
    float* rg        = ws + 152256;
    float* rgamma    = ws + 152320;
    float* rnk       = ws + 152384;
    float* wbeta     = ws + 152448;
    float* wg        = ws + 152512;
    float* wgamma    = ws + 152576;
    float* wnk       = ws + 152640;

    hipMemsetAsync(gates, 0, 135424 * sizeof(float), stream);

    // ---- read head ----
    head_params_kernel<false><<<B_, 512, 0, stream>>>(
        h_tm1, W_rk, b_rk, W_rc, b_rc, W_rs, b_rs, nullptr, nullptr,
        rk, rnk, rs, rbeta, rg, rgamma, nullptr, nullptr);
    scoreE_kernel<0><<<B_ * 256, 256, 0, stream>>>(
        memory, rk, rbeta, rnk, E_r, nMbuf, sum_r, nullptr, nullptr, nullptr);
    conv_kernel<true><<<B_ * 64, 256, 0, stream>>>(
        memory, E_r, read_tm1, sum_r, rg, rgamma, rs, sharp_r, ssum_r, M_read_un);

    // ---- LSTM ----
    gates_splitk_kernel<<<13 * 32, 256, 0, stream>>>(
        inp, M_read_un, h_tm1, W_ih, W_hh, ssum_r, gates);
    lstm_kernel<<<128, 256, 0, stream>>>(gates, b_ih, b_hh, c_tm1, h_out, c_out);

    // ---- write head ----
    head_params_kernel<true><<<B_, 512, 0, stream>>>(
        h_out, W_wk, b_wk, W_wc, b_wc, W_ws, b_ws, W_w, b_w,
        wk, wnk, wss, wbeta, wg, wgamma, e_buf, a_buf);
    scoreE_kernel<1><<<B_ * 256, 256, 0, stream>>>(
        memory, wk, wbeta, wnk, E_w, nMbuf, sum_w, sharp_r, ssum_r, rhead);
    conv_kernel<false><<<B_ * 64, 256, 0, stream>>>(
        nullptr, E_w, write_tm1, sum_w, wg, wgamma, wss, sharp_w, ssum_w, nullptr);
    mout_norm_kernel<<<16384, 256, 0, stream>>>(
        memory, sharp_w, ssum_w, e_buf, a_buf, whead, Mout);
}